// Round 5
// baseline (1557.973 us; speedup 1.0000x reference)
//
#include <hip/hip_runtime.h>
#include <stdint.h>
#include <stddef.h>

#define RPB 128      // rows per bucket (must be power of 2)
#define BCAP 4096    // LDS record capacity per bucket (mean ~1280 for this input)

// ================= helpers =================
__device__ __forceinline__ float bl(unsigned u){ return __uint_as_float(u << 16); }
__device__ __forceinline__ float bh(unsigned u){ return __uint_as_float(u & 0xffff0000u); }
__device__ __forceinline__ float b2f(unsigned short v){ return __uint_as_float(((unsigned)v) << 16); }
__device__ __forceinline__ unsigned short f2bf(float f){
    unsigned u = __float_as_uint(f);
    unsigned r = (u + 0x7fffu + ((u >> 16) & 1u)) >> 16;
    return (unsigned short)r;
}

// ================= mask dtype detection (bool: u8 vs i32 vs f32) =================
__global__ void detect_mask_kernel(const unsigned char* __restrict__ p, int n,
                                   unsigned* __restrict__ flags){
    int i = blockIdx.x*blockDim.x + threadIdx.x;
    if(i >= n) return;
    unsigned char b = p[i];
    unsigned f = 0;
    if((i & 3) && b) f |= 1u;
    if(b == 0x3Fu)   f |= 2u;
    if(f) atomicOr(flags, f);
}
__device__ __forceinline__ float get_mask(const void* p, unsigned flags, int i){
    if((flags & 1u) == 0) return ((const int*)p)[i] ? 1.0f : 0.0f;
    if(flags & 2u)        return ((const float*)p)[i];
    return ((const unsigned char*)p)[i] ? 1.0f : 0.0f;
}

// ================= small weight products: W0c=W0@Wcls, W1c=W1@Wcls, biases =================
__global__ void small_w_kernel(const float* __restrict__ W0, const float* __restrict__ b0,
                               const float* __restrict__ W1, const float* __restrict__ b1,
                               const float* __restrict__ Wcls, const float* __restrict__ bcls,
                               float* __restrict__ W0c, float* __restrict__ W1c,
                               float* __restrict__ b0c, float* __restrict__ b1c)
{
    int t = threadIdx.x;
    for(int i = t; i < 2048; i += 256){
        int d = i >> 4, c = i & 15;
        float s0 = 0.f, s1 = 0.f;
        for(int k = 0; k < 64; k++){
            float wc = Wcls[k*16 + c];
            s0 += W0[d*64 + k]*wc;
            s1 += W1[d*64 + k]*wc;
        }
        W0c[i] = s0; W1c[i] = s1;
    }
    if(t < 16){
        float s0 = 0.f, s1 = 0.f;
        for(int k = 0; k < 64; k++){
            float wc = Wcls[k*16 + t];
            s0 += b0[k]*wc; s1 += b1[k]*wc;
        }
        b0c[t] = s0 + bcls[t];
        b1c[t] = s1;
    }
}

// ====== fused projection: fph(bf16,N*64)=feats0@Wp ; h0c(f32,N*16)=feats0@W0c+b0c ======
__global__ __launch_bounds__(256) void proj_fused0(
    const float* __restrict__ X, const float* __restrict__ Wp,
    const float* __restrict__ W0c, const float* __restrict__ b0c,
    unsigned short* __restrict__ fph, float* __restrict__ h0c, int rows)
{
    __shared__ float Wl[128*64];    // 32 KB
    __shared__ float Wcl[128*16];   // 8 KB
    __shared__ float ftile[32*128]; // 16 KB
    int t = threadIdx.x;
    for(int i = t; i < 2048; i += 256) ((float4*)Wl)[i]  = ((const float4*)Wp)[i];
    for(int i = t; i < 512;  i += 256) ((float4*)Wcl)[i] = ((const float4*)W0c)[i];
    int c4 = (t & 15)*4;
    int col16 = t & 15;
    int r2 = (t >> 4)*2;
    float bc = b0c[col16];
    for(long base = (long)blockIdx.x*32; base < rows; base += (long)gridDim.x*32){
        int nr = min(32, (int)(rows - base));
        __syncthreads();
        for(int i = t; i < nr*32; i += 256){
            int r = i >> 5, q = i & 31;
            ((float4*)ftile)[r*32 + q] = ((const float4*)X)[(base + r)*32 + q];
        }
        __syncthreads();
        float a00=0,a01=0,a02=0,a03=0, a10=0,a11=0,a12=0,a13=0;
        float c0 = bc, c1 = bc;
        #pragma unroll 4
        for(int k = 0; k < 128; k++){
            float4 w = *((const float4*)(Wl + k*64 + c4));
            float wc = Wcl[k*16 + col16];
            float x0 = ftile[r2*128 + k];
            float x1 = ftile[(r2+1)*128 + k];
            a00 += x0*w.x; a01 += x0*w.y; a02 += x0*w.z; a03 += x0*w.w; c0 += x0*wc;
            a10 += x1*w.x; a11 += x1*w.y; a12 += x1*w.z; a13 += x1*w.w; c1 += x1*wc;
        }
        if(r2 < nr){
            ushort4 o; o.x=f2bf(a00); o.y=f2bf(a01); o.z=f2bf(a02); o.w=f2bf(a03);
            *((ushort4*)(fph + (base + r2)*64 + c4)) = o;
            h0c[(base + r2)*16 + col16] = c0;
        }
        if(r2 + 1 < nr){
            ushort4 o; o.x=f2bf(a10); o.y=f2bf(a11); o.z=f2bf(a12); o.w=f2bf(a13);
            *((ushort4*)(fph + (base + r2 + 1)*64 + c4)) = o;
            h0c[(base + r2 + 1)*16 + col16] = c1;
        }
    }
}

// ================= proj to C=16 (bf16 out): Y = X@Wc + bias =================
__global__ __launch_bounds__(256) void proj16_kernel(
    const float* __restrict__ X, const float* __restrict__ Wc,
    const float* __restrict__ biasc, unsigned short* __restrict__ Y, int rows)
{
    __shared__ float Wcl[128*16];   // 8 KB
    __shared__ float ftile[64*128]; // 32 KB
    int t = threadIdx.x;
    for(int i = t; i < 512; i += 256) ((float4*)Wcl)[i] = ((const float4*)Wc)[i];
    int col = t & 15;
    int r4 = (t >> 4)*4;
    float bc = biasc[col];
    for(long base = (long)blockIdx.x*64; base < rows; base += (long)gridDim.x*64){
        int nr = min(64, (int)(rows - base));
        __syncthreads();
        for(int i = t; i < nr*32; i += 256){
            int r = i >> 5, q = i & 31;
            ((float4*)ftile)[r*32 + q] = ((const float4*)X)[(base + r)*32 + q];
        }
        __syncthreads();
        float acc0 = bc, acc1 = bc, acc2 = bc, acc3 = bc;
        #pragma unroll 4
        for(int k = 0; k < 128; k++){
            float wc = Wcl[k*16 + col];
            acc0 += ftile[(r4+0)*128 + k]*wc;
            acc1 += ftile[(r4+1)*128 + k]*wc;
            acc2 += ftile[(r4+2)*128 + k]*wc;
            acc3 += ftile[(r4+3)*128 + k]*wc;
        }
        if(r4+0 < nr) Y[(base + r4 + 0)*16 + col] = f2bf(acc0);
        if(r4+1 < nr) Y[(base + r4 + 1)*16 + col] = f2bf(acc1);
        if(r4+2 < nr) Y[(base + r4 + 2)*16 + col] = f2bf(acc2);
        if(r4+3 < nr) Y[(base + r4 + 3)*16 + col] = f2bf(acc3);
    }
}

// ================= bucket histogram (hot ~9 KB counter array) =================
__global__ __launch_bounds__(256) void bcount_kernel(
    const int* __restrict__ dst0, const int* __restrict__ dst1, const int* __restrict__ dst2,
    int* __restrict__ bcnt, int n, int eg)
{
    long tid = (long)blockIdx.x*blockDim.x + threadIdx.x;
    if(tid >= 3L*eg) return;
    int g = (int)(tid / eg);
    int e = (int)(tid - (long)g*eg);
    const int* dp = g==0 ? dst0 : (g==1 ? dst1 : dst2);
    int row = g*n + dp[e];
    atomicAdd(&bcnt[row >> 7], 1);   // RPB=128
}

// ================= single-block exclusive scan over buckets =================
__global__ __launch_bounds__(256) void bscan_kernel(const int* __restrict__ bcnt,
                                                    int* __restrict__ bbase,
                                                    int* __restrict__ bcur, int nbk)
{
    __shared__ int cs[256];
    __shared__ int cpre[257];
    int t = threadIdx.x;
    int per = (nbk + 255)/256;
    int s = 0;
    for(int k = 0; k < per; k++){
        int i = t*per + k;
        if(i < nbk) s += bcnt[i];
    }
    cs[t] = s;
    __syncthreads();
    if(t == 0){
        int run = 0;
        for(int i = 0; i < 256; i++){ cpre[i] = run; run += cs[i]; }
        cpre[256] = run;
    }
    __syncthreads();
    int run = cpre[t];
    for(int k = 0; k < per; k++){
        int i = t*per + k;
        if(i < nbk){
            bbase[i] = run; bcur[i] = run;
            run += bcnt[i];
        }
    }
    if(t == 0) bbase[nbk] = cpre[256];
}

// ====== partition: packed {src:17b | row_local:7b} into per-bucket windows ======
__global__ __launch_bounds__(256) void part_kernel(
    const int* __restrict__ src0, const int* __restrict__ dst0,
    const int* __restrict__ src1, const int* __restrict__ dst1,
    const int* __restrict__ src2, const int* __restrict__ dst2,
    int* __restrict__ bcur, unsigned* __restrict__ packed, int n, int eg)
{
    long tid = (long)blockIdx.x*blockDim.x + threadIdx.x;
    if(tid >= 3L*eg) return;
    int g = (int)(tid / eg);
    int e = (int)(tid - (long)g*eg);
    const int* sp = g==0 ? src0 : (g==1 ? src1 : src2);
    const int* dp = g==0 ? dst0 : (g==1 ? dst1 : dst2);
    int s = sp[e];
    int row = g*n + dp[e];
    int pos = atomicAdd(&bcur[row >> 7], 1);
    packed[pos] = ((unsigned)s << 7) | (unsigned)(row & (RPB-1));
}

// ====== per-bucket: local rowptr + scores (dst L1-hot) + LDS-CSR + softmax + att write ======
__global__ __launch_bounds__(256) void bucket_kernel(
    const unsigned short* __restrict__ fph, const unsigned* __restrict__ packed,
    const int* __restrict__ bbase, int* __restrict__ rowptr,
    int* __restrict__ csr_src, unsigned short* __restrict__ csr_att,
    int n, int n3)
{
    __shared__ unsigned sPk[BCAP];   // 16 KB
    __shared__ float    sSc[BCAP];   // 16 KB
    __shared__ int lcnt[RPB];
    __shared__ int lptr[RPB+1];
    __shared__ int lcur[RPB];
    int b = blockIdx.x;
    int t = threadIdx.x;
    int base_ = bbase[b];
    int cnt = bbase[b+1] - base_;
    int row0 = b*RPB;
    int rowsIn = min(RPB, n3 - row0);
    bool fast = (cnt <= BCAP);
    if(t < RPB) lcnt[t] = 0;
    if(fast){
        for(int i = t; i < cnt; i += 256) sPk[i] = packed[base_+i];
    }
    __syncthreads();
    for(int i = t; i < cnt; i += 256){
        unsigned pk = fast ? sPk[i] : packed[base_+i];
        atomicAdd(&lcnt[pk & (RPB-1)], 1);
    }
    __syncthreads();
    if(t == 0){
        int run = 0;
        for(int r = 0; r < RPB; r++){ lptr[r] = run; run += lcnt[r]; }
        lptr[RPB] = run;
    }
    __syncthreads();
    if(t < RPB) lcur[t] = lptr[t];
    if(t < rowsIn) rowptr[row0 + t] = base_ + lptr[t];
    if(row0 + rowsIn == n3 && t == 0) rowptr[n3] = base_ + cnt;
    __syncthreads();
    // scores: 8 lanes per edge; src gather random (L2/L3), dst rows within 16 KB slice (L1)
    int gid = t >> 3, l = t & 7;
    int g0 = row0 / n;
    int bound = (g0 + 1)*n;
    const uint4* f4 = (const uint4*)fph;
    for(int k = gid; k < cnt; k += 32){
        unsigned pk = fast ? sPk[k] : packed[base_+k];
        int src = (int)(pk >> 7);
        int rl  = (int)(pk & (RPB-1));
        int rowg = row0 + rl;
        int d = (rowg >= bound) ? (rowg - bound) : (rowg - g0*n);
        uint4 A = f4[(long)src*8 + l];
        uint4 B = f4[(long)d*8 + l];
        float p;
        p  = bl(A.x)*bl(B.x) + bh(A.x)*bh(B.x);
        p += bl(A.y)*bl(B.y) + bh(A.y)*bh(B.y);
        p += bl(A.z)*bl(B.z) + bh(A.z)*bh(B.z);
        p += bl(A.w)*bl(B.w) + bh(A.w)*bh(B.w);
        p += __shfl_xor(p, 1);
        p += __shfl_xor(p, 2);
        p += __shfl_xor(p, 4);
        if(l == 0){
            float sc = p*0.125f;               // / sqrt(64)
            int slot = atomicAdd(&lcur[rl], 1);
            csr_src[base_+slot] = src;         // within hot 16 KB window
            if(fast) sSc[slot] = sc;
            else     csr_att[base_+slot] = f2bf(sc);  // raw score (rare fallback)
        }
    }
    if(!fast) __threadfence();
    __syncthreads();
    // per-row softmax from LDS scores; coalesced bf16 att write
    if(t < rowsIn){
        int beg = lptr[t], end = lptr[t+1];
        if(beg < end){
            float m = -1e30f;
            for(int j = beg; j < end; j++){
                float s = fast ? sSc[j] : b2f(csr_att[base_+j]);
                m = fmaxf(m, s);
            }
            float den = 0.f;
            for(int j = beg; j < end; j++){
                float s = fast ? sSc[j] : b2f(csr_att[base_+j]);
                den += __expf(s - m);
            }
            float inv = 1.0f/(den + 1e-16f);
            for(int j = beg; j < end; j++){
                float s = fast ? sSc[j] : b2f(csr_att[base_+j]);
                csr_att[base_+j] = f2bf(__expf(s - m)*inv);
            }
        }
    }
}

// ====== propagate (CSR gather, blend fused). L1: f32 label_init (graph-shared) ======
template<int L1>
__global__ __launch_bounds__(256) void propagate_kernel(
    const int* __restrict__ rowptr, const int* __restrict__ csr_src,
    const unsigned short* __restrict__ csr_att,
    const float* __restrict__ h_f32, const unsigned short* __restrict__ h_bf,
    unsigned short* __restrict__ h_next, const float* __restrict__ labels,
    const void* __restrict__ maskp, const unsigned* __restrict__ flags, int n)
{
    long tid = (long)blockIdx.x*blockDim.x + threadIdx.x;
    int row = (int)(tid >> 4);
    int c = (int)(tid & 15);
    if(row >= 3*n) return;
    int g = row / n;
    int d = row - g*n;
    int beg = rowptr[row], end = rowptr[row+1];
    float acc = 0.f;
    if(L1){
        for(int j = beg; j < end; j++){
            acc += b2f(csr_att[j]) * h_f32[(long)csr_src[j]*16 + c];
        }
    } else {
        const unsigned short* hg = h_bf + (long)g*n*16;
        int j = beg;
        for(; j + 1 < end; j += 2){
            int s0 = csr_src[j], s1 = csr_src[j+1];
            float w0 = b2f(csr_att[j]), w1 = b2f(csr_att[j+1]);
            acc += w0*b2f(hg[(long)s0*16 + c]) + w1*b2f(hg[(long)s1*16 + c]);
        }
        if(j < end) acc += b2f(csr_att[j])*b2f(hg[(long)csr_src[j]*16 + c]);
    }
    float mk = get_mask(maskp, *flags, d);
    float val = acc*(1.0f - mk) + labels[(long)d*16 + c]*mk;
    h_next[(long)row*16 + c] = f2bf(val);
}

// ================= NS aggregate + attention mix + gate, fully fused =================
__global__ __launch_bounds__(256) void ns_final_kernel(
    const unsigned short* __restrict__ hf, const float* __restrict__ h0c,
    const unsigned short* __restrict__ h1c, const int* __restrict__ nei,
    const float* __restrict__ attn, const float* __restrict__ alpha,
    float* __restrict__ out, int n, int kk)
{
    long tid = (long)blockIdx.x*blockDim.x + threadIdx.x;
    int node = (int)(tid >> 4);
    int c = (int)(tid & 15);
    if(node >= n) return;
    const int* nrow = nei + (long)node*kk;
    float acc = 0.f;
    for(int j = 0; j < kk; j++){
        int nb = nrow[j];
        acc += b2f(h1c[(long)nb*16 + c]);
    }
    float ns = h0c[(long)node*16 + c] + acc*(1.0f/(float)kk);
    float a0 = attn[node*3], a1 = attn[node*3+1], a2 = attn[node*3+2];
    float mx = fmaxf(a0, fmaxf(a1, a2));
    float e0 = __expf(a0-mx), e1 = __expf(a1-mx), e2 = __expf(a2-mx);
    float inv = 1.0f/(e0+e1+e2);
    long gs = (long)n*16;
    long idx = (long)node*16 + c;
    float lp = (e0*b2f(hf[idx]) + e1*b2f(hf[gs + idx]) + e2*b2f(hf[2*gs + idx]))*inv;
    float al = alpha[node];
    float sg = 1.0f/(1.0f + __expf(-al));
    out[idx]        = sg*lp + (1.0f - sg)*ns;
    out[gs + idx]   = lp;
    out[2*gs + idx] = ns;
}

// ================= launch =================
extern "C" void kernel_launch(void* const* d_in, const int* in_sizes, int n_in,
                              void* d_out, int out_size, void* d_ws, size_t ws_size,
                              hipStream_t stream)
{
    const float* feats0     = (const float*)d_in[0];
    const float* feats1     = (const float*)d_in[1];
    const float* W0         = (const float*)d_in[2];
    const float* b0         = (const float*)d_in[3];
    const float* W1         = (const float*)d_in[4];
    const float* b1         = (const float*)d_in[5];
    const float* Wp         = (const float*)d_in[6];
    const float* Wcls       = (const float*)d_in[7];
    const float* bcls       = (const float*)d_in[8];
    const float* alpha      = (const float*)d_in[9];
    const float* attn       = (const float*)d_in[10];
    const float* labels     = (const float*)d_in[11];
    const float* label_init = (const float*)d_in[12];
    const void*  maskp      = d_in[13];
    const int*   nei        = (const int*)d_in[14];
    const int*   src0       = (const int*)d_in[15];
    const int*   dst0       = (const int*)d_in[16];
    const int*   src1       = (const int*)d_in[17];
    const int*   dst1       = (const int*)d_in[18];
    const int*   src2       = (const int*)d_in[19];
    const int*   dst2       = (const int*)d_in[20];

    const int n  = in_sizes[9];          // N
    const int n1 = in_sizes[1] / 128;    // N1
    const int eg = in_sizes[15];         // E per graph
    const int kk = in_sizes[14] / n;     // K
    const int n3 = 3*n;
    const int nbk = (n3 + RPB - 1)/RPB;

    // ---- workspace arena (~74 MB) ----
    char* ws = (char*)d_ws;
    size_t off = 0;
    auto alloc = [&](size_t bytes)->char*{
        char* p = ws + off; off += (bytes + 255) & ~(size_t)255; return p;
    };
    unsigned*       flags  = (unsigned*)      alloc(256);
    unsigned short* fph    = (unsigned short*)alloc((size_t)n*64*2);      // 12.8 MB
    float*          h0c    = (float*)         alloc((size_t)n*16*4);      // 6.4 MB
    unsigned short* h1c    = (unsigned short*)alloc((size_t)n1*16*2);     // 2.56 MB
    float*          W0c    = (float*)         alloc(2048*4);
    float*          W1c    = (float*)         alloc(2048*4);
    float*          b0c    = (float*)         alloc(64);
    float*          b1c    = (float*)         alloc(64);
    int*            bcnt   = (int*)           alloc((size_t)nbk*4);
    int*            bbase  = (int*)           alloc(((size_t)nbk+1)*4);
    int*            bcur   = (int*)           alloc((size_t)nbk*4);
    int*            rowptr = (int*)           alloc(((size_t)n3+1)*4);    // 1.2 MB
    unsigned*       packed = (unsigned*)      alloc((size_t)3*eg*4);      // 12 MB
    int*            csr_src= (int*)           alloc((size_t)3*eg*4);      // 12 MB
    unsigned short* csr_att= (unsigned short*)alloc((size_t)3*eg*2);      // 6 MB
    unsigned short* hA     = (unsigned short*)alloc((size_t)n3*16*2);     // 9.6 MB
    unsigned short* hB     = (unsigned short*)alloc((size_t)n3*16*2);     // 9.6 MB

    // 1. init
    hipMemsetAsync(flags, 0, 4, stream);
    hipMemsetAsync(bcnt, 0, (size_t)nbk*4, stream);
    detect_mask_kernel<<<(n+255)/256, 256, 0, stream>>>((const unsigned char*)maskp, n, flags);

    // 2. tiny weight products
    small_w_kernel<<<1, 256, 0, stream>>>(W0, b0, W1, b1, Wcls, bcls, W0c, W1c, b0c, b1c);

    // 3. projections
    proj_fused0<<<(n+31)/32, 256, 0, stream>>>(feats0, Wp, W0c, b0c, fph, h0c, n);
    proj16_kernel<<<(n1+63)/64, 256, 0, stream>>>(feats1, W1c, b1c, h1c, n1);

    // 4. bucket histogram + scan + partition
    {
        long tot = 3L*eg;
        bcount_kernel<<<(unsigned)((tot+255)/256), 256, 0, stream>>>(dst0, dst1, dst2, bcnt, n, eg);
        bscan_kernel<<<1, 256, 0, stream>>>(bcnt, bbase, bcur, nbk);
        part_kernel<<<(unsigned)((tot+255)/256), 256, 0, stream>>>(
            src0,dst0,src1,dst1,src2,dst2, bcur, packed, n, eg);
    }

    // 5. per-bucket: local rowptr + scores + CSR + softmax (all fused)
    bucket_kernel<<<nbk, 256, 0, stream>>>(fph, packed, bbase, rowptr, csr_src, csr_att, n, n3);

    // 6. LP layers: layer 1 reads f32 label_init (graph-shared); 2,3 read bf16 h.
    {
        long tot = (long)n3*16;
        unsigned gsz = (unsigned)((tot+255)/256);
        propagate_kernel<1><<<gsz, 256, 0, stream>>>(
            rowptr, csr_src, csr_att, label_init, nullptr, hA, labels, maskp, flags, n);
        propagate_kernel<0><<<gsz, 256, 0, stream>>>(
            rowptr, csr_src, csr_att, nullptr, hA, hB, labels, maskp, flags, n);
        propagate_kernel<0><<<gsz, 256, 0, stream>>>(
            rowptr, csr_src, csr_att, nullptr, hB, hA, labels, maskp, flags, n);
    }
    // final h in hA

    // 7. NS aggregate + final mix
    ns_final_kernel<<<(unsigned)(((long)n*16+255)/256), 256, 0, stream>>>(
        hA, h0c, h1c, nei, attn, alpha, (float*)d_out, n, kk);
}

// Round 6
// 629.964 us; speedup vs baseline: 2.4731x; 2.4731x over previous
//
#include <hip/hip_runtime.h>
#include <stdint.h>
#include <stddef.h>

// ================= helpers =================
__device__ __forceinline__ float bl(unsigned u){ return __uint_as_float(u << 16); }
__device__ __forceinline__ float bh(unsigned u){ return __uint_as_float(u & 0xffff0000u); }
__device__ __forceinline__ float b2f(unsigned short v){ return __uint_as_float(((unsigned)v) << 16); }
__device__ __forceinline__ unsigned short f2bf(float f){
    unsigned u = __float_as_uint(f);
    unsigned r = (u + 0x7fffu + ((u >> 16) & 1u)) >> 16;
    return (unsigned short)r;
}

// ====== combined detection: mask dtype (bits 0,1) + label_init uniformity (bit 2) ======
// mask bit0: nonzero byte at offset%4!=0 -> not int32 0/1 layout
// mask bit1: byte == 0x3F -> float32 layout
// bit2: label_init NOT uniform-constant
__global__ void detect_kernel(const unsigned char* __restrict__ mp, int n,
                              const unsigned* __restrict__ li, long li_n,
                              unsigned* __restrict__ flags){
    long i = (long)blockIdx.x*blockDim.x + threadIdx.x;
    unsigned f = 0;
    if(i < n){
        unsigned char b = mp[i];
        if((i & 3) && b) f |= 1u;
        if(b == 0x3Fu)   f |= 2u;
    }
    if(i < li_n){
        if(li[i] != li[0]) f |= 4u;
    }
    if(f) atomicOr(flags, f);
}
__device__ __forceinline__ float get_mask(const void* p, unsigned flags, int i){
    if((flags & 1u) == 0) return ((const int*)p)[i] ? 1.0f : 0.0f;
    if(flags & 2u)        return ((const float*)p)[i];
    return ((const unsigned char*)p)[i] ? 1.0f : 0.0f;
}

// ================= small weight products: W0c=W0@Wcls, W1c=W1@Wcls, biases =================
__global__ void small_w_kernel(const float* __restrict__ W0, const float* __restrict__ b0,
                               const float* __restrict__ W1, const float* __restrict__ b1,
                               const float* __restrict__ Wcls, const float* __restrict__ bcls,
                               float* __restrict__ W0c, float* __restrict__ W1c,
                               float* __restrict__ b0c, float* __restrict__ b1c)
{
    int t = threadIdx.x;
    for(int i = t; i < 2048; i += 256){
        int d = i >> 4, c = i & 15;
        float s0 = 0.f, s1 = 0.f;
        for(int k = 0; k < 64; k++){
            float wc = Wcls[k*16 + c];
            s0 += W0[d*64 + k]*wc;
            s1 += W1[d*64 + k]*wc;
        }
        W0c[i] = s0; W1c[i] = s1;
    }
    if(t < 16){
        float s0 = 0.f, s1 = 0.f;
        for(int k = 0; k < 64; k++){
            float wc = Wcls[k*16 + t];
            s0 += b0[k]*wc; s1 += b1[k]*wc;
        }
        b0c[t] = s0 + bcls[t];
        b1c[t] = s1;
    }
}

// ====== fused projection: fph(bf16,N*64)=feats0@Wp ; h0c(f32,N*16)=feats0@W0c+b0c ======
__global__ __launch_bounds__(256) void proj_fused0(
    const float* __restrict__ X, const float* __restrict__ Wp,
    const float* __restrict__ W0c, const float* __restrict__ b0c,
    unsigned short* __restrict__ fph, float* __restrict__ h0c, int rows)
{
    __shared__ float Wl[128*64];    // 32 KB
    __shared__ float Wcl[128*16];   // 8 KB
    __shared__ float ftile[32*128]; // 16 KB
    int t = threadIdx.x;
    for(int i = t; i < 2048; i += 256) ((float4*)Wl)[i]  = ((const float4*)Wp)[i];
    for(int i = t; i < 512;  i += 256) ((float4*)Wcl)[i] = ((const float4*)W0c)[i];
    int c4 = (t & 15)*4;
    int col16 = t & 15;
    int r2 = (t >> 4)*2;
    float bc = b0c[col16];
    for(long base = (long)blockIdx.x*32; base < rows; base += (long)gridDim.x*32){
        int nr = min(32, (int)(rows - base));
        __syncthreads();
        for(int i = t; i < nr*32; i += 256){
            int r = i >> 5, q = i & 31;
            ((float4*)ftile)[r*32 + q] = ((const float4*)X)[(base + r)*32 + q];
        }
        __syncthreads();
        float a00=0,a01=0,a02=0,a03=0, a10=0,a11=0,a12=0,a13=0;
        float c0 = bc, c1 = bc;
        #pragma unroll 4
        for(int k = 0; k < 128; k++){
            float4 w = *((const float4*)(Wl + k*64 + c4));
            float wc = Wcl[k*16 + col16];
            float x0 = ftile[r2*128 + k];
            float x1 = ftile[(r2+1)*128 + k];
            a00 += x0*w.x; a01 += x0*w.y; a02 += x0*w.z; a03 += x0*w.w; c0 += x0*wc;
            a10 += x1*w.x; a11 += x1*w.y; a12 += x1*w.z; a13 += x1*w.w; c1 += x1*wc;
        }
        if(r2 < nr){
            ushort4 o; o.x=f2bf(a00); o.y=f2bf(a01); o.z=f2bf(a02); o.w=f2bf(a03);
            *((ushort4*)(fph + (base + r2)*64 + c4)) = o;
            h0c[(base + r2)*16 + col16] = c0;
        }
        if(r2 + 1 < nr){
            ushort4 o; o.x=f2bf(a10); o.y=f2bf(a11); o.z=f2bf(a12); o.w=f2bf(a13);
            *((ushort4*)(fph + (base + r2 + 1)*64 + c4)) = o;
            h0c[(base + r2 + 1)*16 + col16] = c1;
        }
    }
}

// ================= proj to C=16 (bf16 out): Y = X@Wc + bias =================
__global__ __launch_bounds__(256) void proj16_kernel(
    const float* __restrict__ X, const float* __restrict__ Wc,
    const float* __restrict__ biasc, unsigned short* __restrict__ Y, int rows)
{
    __shared__ float Wcl[128*16];   // 8 KB
    __shared__ float ftile[64*128]; // 32 KB
    int t = threadIdx.x;
    for(int i = t; i < 512; i += 256) ((float4*)Wcl)[i] = ((const float4*)Wc)[i];
    int col = t & 15;
    int r4 = (t >> 4)*4;
    float bc = biasc[col];
    for(long base = (long)blockIdx.x*64; base < rows; base += (long)gridDim.x*64){
        int nr = min(64, (int)(rows - base));
        __syncthreads();
        for(int i = t; i < nr*32; i += 256){
            int r = i >> 5, q = i & 31;
            ((float4*)ftile)[r*32 + q] = ((const float4*)X)[(base + r)*32 + q];
        }
        __syncthreads();
        float acc0 = bc, acc1 = bc, acc2 = bc, acc3 = bc;
        #pragma unroll 4
        for(int k = 0; k < 128; k++){
            float wc = Wcl[k*16 + col];
            acc0 += ftile[(r4+0)*128 + k]*wc;
            acc1 += ftile[(r4+1)*128 + k]*wc;
            acc2 += ftile[(r4+2)*128 + k]*wc;
            acc3 += ftile[(r4+3)*128 + k]*wc;
        }
        if(r4+0 < nr) Y[(base + r4 + 0)*16 + col] = f2bf(acc0);
        if(r4+1 < nr) Y[(base + r4 + 1)*16 + col] = f2bf(acc1);
        if(r4+2 < nr) Y[(base + r4 + 2)*16 + col] = f2bf(acc2);
        if(r4+3 < nr) Y[(base + r4 + 3)*16 + col] = f2bf(acc3);
    }
}

// ================= CSR build: degree count =================
__global__ __launch_bounds__(256) void count_kernel(
    const int* __restrict__ dst0, const int* __restrict__ dst1, const int* __restrict__ dst2,
    int* __restrict__ deg, int n, int eg)
{
    long tid = (long)blockIdx.x*blockDim.x + threadIdx.x;
    if(tid >= 3L*eg) return;
    int g = (int)(tid / eg);
    int e = (int)(tid - (long)g*eg);
    const int* dp = g==0 ? dst0 : (g==1 ? dst1 : dst2);
    atomicAdd(&deg[(long)g*n + dp[e]], 1);
}

// ================= scan: blockwise inclusive (1024 elems/block) =================
__global__ __launch_bounds__(256) void scanA_kernel(const int* __restrict__ deg,
                                                    int* __restrict__ incl,
                                                    int* __restrict__ bsum, int n3)
{
    __shared__ int sh[256];
    int t = threadIdx.x;
    long base = (long)blockIdx.x*1024 + t*4;
    int v0=0,v1=0,v2=0,v3=0;
    if(base   < n3) v0 = deg[base];
    if(base+1 < n3) v1 = deg[base+1];
    if(base+2 < n3) v2 = deg[base+2];
    if(base+3 < n3) v3 = deg[base+3];
    int tot = v0+v1+v2+v3;
    sh[t] = tot;
    __syncthreads();
    for(int ofs = 1; ofs < 256; ofs <<= 1){
        int add = (t >= ofs) ? sh[t-ofs] : 0;
        __syncthreads();
        sh[t] += add;
        __syncthreads();
    }
    int pre = sh[t] - tot;
    if(t == 255) bsum[blockIdx.x] = sh[255];
    int s0 = pre+v0, s1 = s0+v1, s2 = s1+v2, s3 = s2+v3;
    if(base   < n3) incl[base]   = s0;
    if(base+1 < n3) incl[base+1] = s1;
    if(base+2 < n3) incl[base+2] = s2;
    if(base+3 < n3) incl[base+3] = s3;
}

__global__ __launch_bounds__(512) void scanB_kernel(int* __restrict__ bsum, int nb)
{
    __shared__ int sh[512];
    int t = threadIdx.x;
    int v = (t < nb) ? bsum[t] : 0;
    sh[t] = v;
    __syncthreads();
    for(int ofs = 1; ofs < 512; ofs <<= 1){
        int add = (t >= ofs) ? sh[t-ofs] : 0;
        __syncthreads();
        sh[t] += add;
        __syncthreads();
    }
    if(t < nb) bsum[t] = sh[t] - v;   // exclusive
}

__global__ __launch_bounds__(256) void scanC_kernel(const int* __restrict__ incl,
                                                    const int* __restrict__ boff,
                                                    int* __restrict__ rowptr,
                                                    int* __restrict__ cursor, int n3)
{
    int i = blockIdx.x*blockDim.x + threadIdx.x;
    if(i >= n3) return;
    int ex = (i == 0) ? 0 : (incl[i-1] + boff[(i-1) >> 10]);
    rowptr[i] = ex;
    cursor[i] = ex;
    if(i == n3-1) rowptr[n3] = incl[i] + boff[i >> 10];
}

// ====== FUSED scores + packed-record scatter, 2-edge ILP per 8-lane group ======
// 4 independent 128B gathers in flight per group; two independent atomic chains.
__global__ __launch_bounds__(256) void score_scatter_packed(
    const unsigned short* __restrict__ fph,
    const int* __restrict__ src0, const int* __restrict__ dst0,
    const int* __restrict__ src1, const int* __restrict__ dst1,
    const int* __restrict__ src2, const int* __restrict__ dst2,
    int* __restrict__ cursor, uint2* __restrict__ rec, int n, int eg)
{
    long tid = (long)blockIdx.x*blockDim.x + threadIdx.x;
    long gid = tid >> 3;
    long tot = 3L*eg;
    long e0 = gid*2;
    if(e0 >= tot) return;
    int l = threadIdx.x & 7;
    bool has1 = (e0 + 1 < tot);
    long e1 = has1 ? (e0 + 1) : e0;
    int g0 = (int)(e0 / eg); int i0 = (int)(e0 - (long)g0*eg);
    int g1 = (int)(e1 / eg); int i1 = (int)(e1 - (long)g1*eg);
    const int* sp0 = g0==0 ? src0 : (g0==1 ? src1 : src2);
    const int* dp0 = g0==0 ? dst0 : (g0==1 ? dst1 : dst2);
    const int* sp1 = g1==0 ? src0 : (g1==1 ? src1 : src2);
    const int* dp1 = g1==0 ? dst0 : (g1==1 ? dst1 : dst2);
    int s0 = sp0[i0], d0 = dp0[i0];
    int s1 = sp1[i1], d1 = dp1[i1];
    const uint4* f4 = (const uint4*)fph;
    uint4 A0 = f4[(long)s0*8 + l];
    uint4 B0 = f4[(long)d0*8 + l];
    uint4 A1 = f4[(long)s1*8 + l];
    uint4 B1 = f4[(long)d1*8 + l];
    float p0, p1;
    p0  = bl(A0.x)*bl(B0.x) + bh(A0.x)*bh(B0.x);
    p0 += bl(A0.y)*bl(B0.y) + bh(A0.y)*bh(B0.y);
    p0 += bl(A0.z)*bl(B0.z) + bh(A0.z)*bh(B0.z);
    p0 += bl(A0.w)*bl(B0.w) + bh(A0.w)*bh(B0.w);
    p1  = bl(A1.x)*bl(B1.x) + bh(A1.x)*bh(B1.x);
    p1 += bl(A1.y)*bl(B1.y) + bh(A1.y)*bh(B1.y);
    p1 += bl(A1.z)*bl(B1.z) + bh(A1.z)*bh(B1.z);
    p1 += bl(A1.w)*bl(B1.w) + bh(A1.w)*bh(B1.w);
    p0 += __shfl_xor(p0, 1);  p1 += __shfl_xor(p1, 1);
    p0 += __shfl_xor(p0, 2);  p1 += __shfl_xor(p1, 2);
    p0 += __shfl_xor(p0, 4);  p1 += __shfl_xor(p1, 4);
    if(l == 0){
        int pos0 = atomicAdd(&cursor[(long)g0*n + d0], 1);
        uint2 r0; r0.x = (unsigned)s0; r0.y = __float_as_uint(p0*0.125f);
        rec[pos0] = r0;
        if(has1){
            int pos1 = atomicAdd(&cursor[(long)g1*n + d1], 1);
            uint2 r1; r1.x = (unsigned)s1; r1.y = __float_as_uint(p1*0.125f);
            rec[pos1] = r1;
        }
    }
}

// ====== per-row softmax: rec[].y := exp(s-m)/den ======
__global__ __launch_bounds__(256) void row_softmax_kernel(const int* __restrict__ rowptr,
                                                          uint2* __restrict__ rec, int n3)
{
    int i = blockIdx.x*blockDim.x + threadIdx.x;
    if(i >= n3) return;
    int beg = rowptr[i], end = rowptr[i+1];
    if(beg == end) return;
    float m = -1e30f;
    for(int j = beg; j < end; j++) m = fmaxf(m, __uint_as_float(rec[j].y));
    float den = 0.f;
    for(int j = beg; j < end; j++) den += __expf(__uint_as_float(rec[j].y) - m);
    float inv = 1.0f/(den + 1e-16f);
    for(int j = beg; j < end; j++)
        rec[j].y = __float_as_uint(__expf(__uint_as_float(rec[j].y) - m)*inv);
}

// ====== propagate (CSR record gather, blend fused).
//  L1 + uniform label_init (flag bit2 clear): zero-gather shortcut, val = c0·[deg>0].
//  L1 + non-uniform: f32 gather fallback. else: bf16 h input per graph. ======
template<int L1>
__global__ __launch_bounds__(256) void propagate_rec_kernel(
    const int* __restrict__ rowptr, const uint2* __restrict__ rec,
    const float* __restrict__ h_in_f32, const unsigned short* __restrict__ h_in_bf,
    unsigned short* __restrict__ h_next, const float* __restrict__ labels,
    const void* __restrict__ maskp, const unsigned* __restrict__ flags, int n)
{
    long tid = (long)blockIdx.x*blockDim.x + threadIdx.x;
    int row = (int)(tid >> 4);
    int c = (int)(tid & 15);
    if(row >= 3*n) return;
    int g = row / n;
    int d = row - g*n;
    int beg = rowptr[row], end = rowptr[row+1];
    unsigned fl = *flags;
    float acc = 0.f;
    if(L1){
        if(!(fl & 4u)){
            // label_init uniform: sum(att)=1 analytically for non-empty rows
            acc = (end > beg) ? h_in_f32[0] : 0.f;
        } else {
            for(int j = beg; j < end; j++){
                uint2 r = rec[j];
                acc += __uint_as_float(r.y) * h_in_f32[(long)r.x*16 + c];
            }
        }
    } else {
        const unsigned short* hg = h_in_bf + (long)g*n*16;
        int j = beg;
        for(; j + 1 < end; j += 2){
            uint2 r0 = rec[j], r1 = rec[j+1];
            acc += __uint_as_float(r0.y)*b2f(hg[(long)r0.x*16 + c])
                 + __uint_as_float(r1.y)*b2f(hg[(long)r1.x*16 + c]);
        }
        if(j < end){
            uint2 r0 = rec[j];
            acc += __uint_as_float(r0.y)*b2f(hg[(long)r0.x*16 + c]);
        }
    }
    float mk = get_mask(maskp, fl, d);
    float val = acc*(1.0f - mk) + labels[(long)d*16 + c]*mk;
    h_next[(long)row*16 + c] = f2bf(val);
}

// ================= NS aggregate + attention mix + gate, fully fused =================
__global__ __launch_bounds__(256) void ns_final_kernel(
    const unsigned short* __restrict__ hf, const float* __restrict__ h0c,
    const unsigned short* __restrict__ h1c, const int* __restrict__ nei,
    const float* __restrict__ attn, const float* __restrict__ alpha,
    float* __restrict__ out, int n, int kk)
{
    long tid = (long)blockIdx.x*blockDim.x + threadIdx.x;
    int node = (int)(tid >> 4);
    int c = (int)(tid & 15);
    if(node >= n) return;
    const int* nrow = nei + (long)node*kk;
    float acc = 0.f;
    for(int j = 0; j < kk; j++){
        int nb = nrow[j];
        acc += b2f(h1c[(long)nb*16 + c]);
    }
    float ns = h0c[(long)node*16 + c] + acc*(1.0f/(float)kk);
    float a0 = attn[node*3], a1 = attn[node*3+1], a2 = attn[node*3+2];
    float mx = fmaxf(a0, fmaxf(a1, a2));
    float e0 = __expf(a0-mx), e1 = __expf(a1-mx), e2 = __expf(a2-mx);
    float inv = 1.0f/(e0+e1+e2);
    long gs = (long)n*16;
    long idx = (long)node*16 + c;
    float lp = (e0*b2f(hf[idx]) + e1*b2f(hf[gs + idx]) + e2*b2f(hf[2*gs + idx]))*inv;
    float al = alpha[node];
    float sg = 1.0f/(1.0f + __expf(-al));
    out[idx]        = sg*lp + (1.0f - sg)*ns;
    out[gs + idx]   = lp;
    out[2*gs + idx] = ns;
}

// ================= launch =================
extern "C" void kernel_launch(void* const* d_in, const int* in_sizes, int n_in,
                              void* d_out, int out_size, void* d_ws, size_t ws_size,
                              hipStream_t stream)
{
    const float* feats0     = (const float*)d_in[0];
    const float* feats1     = (const float*)d_in[1];
    const float* W0         = (const float*)d_in[2];
    const float* b0         = (const float*)d_in[3];
    const float* W1         = (const float*)d_in[4];
    const float* b1         = (const float*)d_in[5];
    const float* Wp         = (const float*)d_in[6];
    const float* Wcls       = (const float*)d_in[7];
    const float* bcls       = (const float*)d_in[8];
    const float* alpha      = (const float*)d_in[9];
    const float* attn       = (const float*)d_in[10];
    const float* labels     = (const float*)d_in[11];
    const float* label_init = (const float*)d_in[12];
    const void*  maskp      = d_in[13];
    const int*   nei        = (const int*)d_in[14];
    const int*   src0       = (const int*)d_in[15];
    const int*   dst0       = (const int*)d_in[16];
    const int*   src1       = (const int*)d_in[17];
    const int*   dst1       = (const int*)d_in[18];
    const int*   src2       = (const int*)d_in[19];
    const int*   dst2       = (const int*)d_in[20];

    const int n  = in_sizes[9];          // N
    const int n1 = in_sizes[1] / 128;    // N1
    const int eg = in_sizes[15];         // E per graph
    const int kk = in_sizes[14] / n;     // K
    const int n3 = 3*n;

    // ---- workspace arena (~70 MB) ----
    char* ws = (char*)d_ws;
    size_t off = 0;
    auto alloc = [&](size_t bytes)->char*{
        char* p = ws + off; off += (bytes + 255) & ~(size_t)255; return p;
    };
    unsigned*       flags  = (unsigned*)      alloc(256);
    unsigned short* fph    = (unsigned short*)alloc((size_t)n*64*2);      // 12.8 MB
    float*          h0c    = (float*)         alloc((size_t)n*16*4);      // 6.4 MB
    unsigned short* h1c    = (unsigned short*)alloc((size_t)n1*16*2);     // 2.56 MB
    float*          W0c    = (float*)         alloc(2048*4);
    float*          W1c    = (float*)         alloc(2048*4);
    float*          b0c    = (float*)         alloc(64);
    float*          b1c    = (float*)         alloc(64);
    int*            deg    = (int*)           alloc((size_t)n3*4);        // aliases incl
    int*            cursor = (int*)           alloc((size_t)n3*4);
    int*            bsum   = (int*)           alloc(512*4);
    int*            rowptr = (int*)           alloc(((size_t)n3+1)*4);
    uint2*          rec    = (uint2*)         alloc((size_t)3*eg*8);      // 24 MB
    unsigned short* hA     = (unsigned short*)alloc((size_t)n3*16*2);     // 9.6 MB
    unsigned short* hB     = (unsigned short*)alloc((size_t)n3*16*2);     // 9.6 MB
    int* incl = deg;  // safe alias: scanA reads deg[i] before writing incl[i], per-thread

    // 1. init + combined detection (mask dtype + label_init uniformity)
    hipMemsetAsync(flags, 0, 4, stream);
    hipMemsetAsync(deg, 0, (size_t)n3*4, stream);
    {
        long li_n = (long)n*16;
        long tot = li_n;   // >= n
        detect_kernel<<<(unsigned)((tot+255)/256), 256, 0, stream>>>(
            (const unsigned char*)maskp, n, (const unsigned*)label_init, li_n, flags);
    }

    // 2. tiny weight products
    small_w_kernel<<<1, 256, 0, stream>>>(W0, b0, W1, b1, Wcls, bcls, W0c, W1c, b0c, b1c);

    // 3. projections
    proj_fused0<<<(n+31)/32, 256, 0, stream>>>(feats0, Wp, W0c, b0c, fph, h0c, n);
    proj16_kernel<<<(n1+63)/64, 256, 0, stream>>>(feats1, W1c, b1c, h1c, n1);

    // 4. CSR rowptr build
    {
        long tot = 3L*eg;
        count_kernel<<<(unsigned)((tot+255)/256), 256, 0, stream>>>(dst0, dst1, dst2, deg, n, eg);
    }
    int nb = (n3 + 1023)/1024;
    scanA_kernel<<<nb, 256, 0, stream>>>(deg, incl, bsum, n3);
    scanB_kernel<<<1, 512, 0, stream>>>(bsum, nb);
    scanC_kernel<<<(n3+255)/256, 256, 0, stream>>>(incl, bsum, rowptr, cursor, n3);

    // 5. FUSED scores + packed-record scatter (2-edge ILP)
    {
        long groups = (3L*eg + 1)/2;
        long tthreads = groups*8;
        score_scatter_packed<<<(unsigned)((tthreads+255)/256), 256, 0, stream>>>(
            fph, src0,dst0,src1,dst1,src2,dst2, cursor, rec, n, eg);
    }
    // 6. per-row softmax normalize (in-place in records; shared by all 3 layers)
    row_softmax_kernel<<<(n3+255)/256, 256, 0, stream>>>(rowptr, rec, n3);

    // 7. LP layers: layer 1 uses uniform-label_init shortcut (or f32 gather fallback);
    //    layers 2,3 read bf16 h. Blend fused everywhere.
    {
        long tot = (long)n3*16;
        unsigned gsz = (unsigned)((tot+255)/256);
        propagate_rec_kernel<1><<<gsz, 256, 0, stream>>>(
            rowptr, rec, label_init, nullptr, hA, labels, maskp, flags, n);
        propagate_rec_kernel<0><<<gsz, 256, 0, stream>>>(
            rowptr, rec, nullptr, hA, hB, labels, maskp, flags, n);
        propagate_rec_kernel<0><<<gsz, 256, 0, stream>>>(
            rowptr, rec, nullptr, hB, hA, labels, maskp, flags, n);
    }
    // final h in hA

    // 8. NS aggregate + final mix
    ns_final_kernel<<<(unsigned)(((long)n*16+255)/256), 256, 0, stream>>>(
        hA, h0c, h1c, nei, attn, alpha, (float*)d_out, n, kk);
}